// Round 10
// baseline (1213.651 us; speedup 1.0000x reference)
//
#include <hip/hip_runtime.h>
#include <hip/hip_fp16.h>

#define N_IN_SZ   400000
#define N_OUT_SZ  200000
#define K_OFF     27
#define R_RULES   200000
#define NC        32
#define TOTAL_E   (K_OFF * R_RULES)     // 5,400,000

// chunk = o >> 6 (64 outputs); buckets chunk-major: b = chunk*27 + k
#define CH_SHIFT  6
#define CH_ROWS   64
#define NCHUNK    3125                   // 200000/64 exactly
#define NB        (NCHUNK * K_OFF)       // 84,375
#define NB_PAD    84992                  // 83*1024
#define N_CNT4    (NB_PAD / 4)           // 21,248
#define NSCANBLK  83

#define HIST_BLK  8
#define RPH       25000

typedef unsigned int u32;
typedef unsigned long long u64;
typedef __attribute__((ext_vector_type(8))) short bf16x8;
typedef __attribute__((ext_vector_type(4))) float f32x4;

// ---------------- ws layout (identical to R9 — proven to fit) ----------------
#define SORT_OFF    0ull
#define A_OFF       21600000ull
#define BSUM_OFF    (A_OFF + (u64)NB_PAD * 4)
#define BOFF_OFF    (BSUM_OFF + 1024ull)
#define WS_NEW_NEEDED (BOFF_OFF + 1024ull)         // 21,942,016

#define ACC_WORDS  (N_OUT_SZ * 16)
#define WS_F16_NEEDED  ((size_t)ACC_WORDS * 4)

__device__ __forceinline__ u32 pack_bf16(float lo, float hi) {
    return (__float_as_uint(hi) & 0xFFFF0000u) | (__float_as_uint(lo) >> 16);
}

// ===========================================================================
// sort pipeline (verbatim R9). entry = (o&63)<<24 | k<<19 | irow
// ===========================================================================
__global__ __launch_bounds__(256) void zero_cnt_kernel(uint4* __restrict__ A4)
{
    int i = blockIdx.x * 256 + threadIdx.x;
    if (i < N_CNT4) A4[i] = make_uint4(0, 0, 0, 0);
}

__global__ __launch_bounds__(256) void hist_kernel(
    const int* __restrict__ out_idx, u32* __restrict__ A)
{
    __shared__ u32 lh[NCHUNK];
    for (int t = threadIdx.x; t < NCHUNK; t += 256) lh[t] = 0;
    __syncthreads();
    const int k    = blockIdx.y;
    const int base = blockIdx.x * RPH;
    for (int r = base + threadIdx.x; r < base + RPH; r += 256)
        atomicAdd(&lh[((u32)out_idx[(size_t)k * R_RULES + r]) >> CH_SHIFT], 1u);
    __syncthreads();
    for (int t = threadIdx.x; t < NCHUNK; t += 256) {
        u32 v = lh[t];
        if (v) atomicAdd(&A[(u32)t * K_OFF + (u32)k], v);
    }
}

__global__ __launch_bounds__(256) void blocksum_kernel(
    const uint4* __restrict__ A4, u32* __restrict__ bsum)
{
    int i4 = blockIdx.x * 256 + threadIdx.x;
    uint4 c = A4[i4];
    u32 s = c.x + c.y + c.z + c.w;
    int lane = threadIdx.x & 63;
#pragma unroll
    for (int off = 32; off > 0; off >>= 1)
        s += __shfl_down(s, off);
    __shared__ u32 ws[4];
    int wid = threadIdx.x >> 6;
    if (lane == 0) ws[wid] = s;
    __syncthreads();
    if (threadIdx.x == 0)
        bsum[blockIdx.x] = ws[0] + ws[1] + ws[2] + ws[3];
}

__global__ __launch_bounds__(256) void scanblk_kernel(
    const u32* __restrict__ bsum, u32* __restrict__ boff)
{
    __shared__ u32 lds[NSCANBLK];
    int t = threadIdx.x;
    if (t < NSCANBLK) lds[t] = bsum[t];
    __syncthreads();
    if (t == 0) {
        u32 run = 0;
        for (int i = 0; i < NSCANBLK; ++i) { u32 v = lds[i]; lds[i] = run; run += v; }
    }
    __syncthreads();
    if (t < NSCANBLK) boff[t] = lds[t];
}

__global__ __launch_bounds__(256) void scanwrite_kernel(
    uint4* __restrict__ A4, const u32* __restrict__ boff)
{
    int i4 = blockIdx.x * 256 + threadIdx.x;
    uint4 c = A4[i4];
    u32 lsum = c.x + c.y + c.z + c.w;
    u32 s = lsum;
    int lane = threadIdx.x & 63;
#pragma unroll
    for (int off = 1; off < 64; off <<= 1) {
        u32 v = __shfl_up(s, off);
        if (lane >= off) s += v;
    }
    __shared__ u32 wsum[4], wbase[4];
    int wid = threadIdx.x >> 6;
    if (lane == 63) wsum[wid] = s;
    __syncthreads();
    if (threadIdx.x == 0) {
        u32 run = 0;
        for (int w = 0; w < 4; ++w) { wbase[w] = run; run += wsum[w]; }
    }
    __syncthreads();
    u32 base = boff[blockIdx.x] + wbase[wid] + (s - lsum);
    uint4 st;
    st.x = base;
    st.y = st.x + c.x;
    st.z = st.y + c.y;
    st.w = st.z + c.z;
    A4[i4] = st;
}

__global__ __launch_bounds__(256) void fill_kernel(
    const int* __restrict__ in_idx, const int* __restrict__ out_idx,
    u32* __restrict__ A, u32* __restrict__ sorted)
{
    __shared__ u32 lh[NCHUNK];
    __shared__ u32 lbase[NCHUNK];
    const int k    = blockIdx.y;
    const int base = blockIdx.x * RPH;

    for (int t = threadIdx.x; t < NCHUNK; t += 256) lh[t] = 0;
    __syncthreads();
    for (int r = base + threadIdx.x; r < base + RPH; r += 256)
        atomicAdd(&lh[((u32)out_idx[(size_t)k * R_RULES + r]) >> CH_SHIFT], 1u);
    __syncthreads();
    for (int t = threadIdx.x; t < NCHUNK; t += 256) {
        u32 v = lh[t];
        if (v) lbase[t] = atomicAdd(&A[(u32)t * K_OFF + (u32)k], v);
    }
    __syncthreads();
    for (int t = threadIdx.x; t < NCHUNK; t += 256) lh[t] = 0;
    __syncthreads();
    for (int r = base + threadIdx.x; r < base + RPH; r += 256) {
        u32 o  = (u32)out_idx[(size_t)k * R_RULES + r];
        u32 iv = (u32)in_idx[(size_t)k * R_RULES + r];
        u32 ch = o >> CH_SHIFT;
        u32 off = atomicAdd(&lh[ch], 1u);
        sorted[lbase[ch] + off] =
            ((o & (u32)(CH_ROWS - 1)) << 24) | ((u32)k << 19) | iv;
    }
}

// ===========================================================================
// gather (MFMA): block = 64-row chunk. Wave owns buckets k == wave (mod 4).
// Per tile: 16 sorted entries -> A-frag (each lane 32B of one feat row),
// B-frag = W[k] (loaded once/bucket), 2x mfma_16x16x32_bf16 -> C scatter
// via ds_add_f32 into 65x33 LDS acc (row 64 = trash for masked tails).
// 2-tile ping-pong with NAMED registers; entry words broadcast via shfl.
// Zero global atomics; direct biased store.
// ===========================================================================
__global__ __launch_bounds__(256, 4) void gather_mfma_kernel(
    const float* __restrict__ feat,    // [N_IN, 32]
    const float* __restrict__ weight,  // [27*32, 32]
    const u32*   __restrict__ sorted,  // [TOTAL_E]
    const u32*   __restrict__ A,       // post-fill: A[b] = end_b
    const float* __restrict__ bias,
    float*       __restrict__ out)     // [N_OUT, 32]
{
    __shared__ float acc[65 * 33];     // 8580 B
    for (int t = threadIdx.x; t < 65 * 33; t += 256) acc[t] = 0.0f;
    __syncthreads();

    const int chunk = blockIdx.x;
    const int wave  = threadIdx.x >> 6;
    const int lane  = threadIdx.x & 63;
    const int r16   = lane & 15;       // entry-in-tile (A) / channel (C)
    const int quad  = lane >> 4;       // k-octet selector

    for (int k = wave; k < K_OFF; k += 4) {
        const u32 b  = (u32)chunk * K_OFF + (u32)k;
        const u32 bs = (b > 0) ? A[b - 1] : 0u;
        const u32 be = A[b];
        if (be <= bs) continue;

        // B fragments for W[k]: B[kk][n], kk = quad*8 + e, n = r16 (+16 hi)
        union { u32 w[4]; bf16x8 v; } bl, bh;
        const float* wk = weight + (size_t)k * NC * NC;
#pragma unroll
        for (int ee = 0; ee < 4; ++ee) {
            const int kk0 = quad * 8 + 2 * ee;
            bl.w[ee] = pack_bf16(wk[(size_t)kk0 * NC + r16],
                                 wk[(size_t)(kk0 + 1) * NC + r16]);
            bh.w[ee] = pack_bf16(wk[(size_t)kk0 * NC + 16 + r16],
                                 wk[(size_t)(kk0 + 1) * NC + 16 + r16]);
        }

        // ---- prologue: stage + load tile A ----
        u32 tb = bs;
        u32 ewA = 0x40000000u;                       // ol=64 trash, irow=0
        if (lane < 16 && tb + (u32)lane < be) ewA = sorted[tb + lane];
        u32 emA = (u32)__shfl((int)ewA, r16);
        const float4* pA = reinterpret_cast<const float4*>(
            feat + (size_t)(emA & 0x7FFFFu) * NC) + quad * 2;
        float4 qA0 = pA[0], qA1 = pA[1];

        while (true) {
            const u32 nb = tb + 16;
            const bool more = nb < be;               // wave-uniform
            u32 ewB = 0x40000000u;
            float4 qB0, qB1;
            if (more) {                              // stage + load tile B
                if (lane < 16 && nb + (u32)lane < be) ewB = sorted[nb + lane];
                u32 emB = (u32)__shfl((int)ewB, r16);
                const float4* pB = reinterpret_cast<const float4*>(
                    feat + (size_t)(emB & 0x7FFFFu) * NC) + quad * 2;
                qB0 = pB[0]; qB1 = pB[1];
            }

            // ---- compute tile A ----
            union { u32 w[4]; bf16x8 v; } au;
            au.w[0] = pack_bf16(qA0.x, qA0.y);
            au.w[1] = pack_bf16(qA0.z, qA0.w);
            au.w[2] = pack_bf16(qA1.x, qA1.y);
            au.w[3] = pack_bf16(qA1.z, qA1.w);
            f32x4 c0 = {0.f, 0.f, 0.f, 0.f};
            f32x4 c1 = {0.f, 0.f, 0.f, 0.f};
            c0 = __builtin_amdgcn_mfma_f32_16x16x32_bf16(au.v, bl.v, c0, 0, 0, 0);
            c1 = __builtin_amdgcn_mfma_f32_16x16x32_bf16(au.v, bh.v, c1, 0, 0, 0);
#pragma unroll
            for (int rg = 0; rg < 4; ++rg) {
                const u32 ec = (u32)__shfl((int)ewA, quad * 4 + rg);
                const int ol = (int)(ec >> 24);
                atomicAdd(&acc[ol * 33 + r16],      c0[rg]);   // ds_add_f32
                atomicAdd(&acc[ol * 33 + 16 + r16], c1[rg]);
            }

            if (!more) break;
            ewA = ewB; qA0 = qB0; qA1 = qB1;
            tb = nb;
        }
    }
    __syncthreads();

    const int obase = chunk << CH_SHIFT;             // 3125*64 = 200000 exact
    for (int t = threadIdx.x; t < CH_ROWS * NC; t += 256) {
        const int o = t >> 5, c = t & 31;
        out[(size_t)(obase + o) * NC + c] = acc[o * 33 + c] + bias[c];
    }
}

// ===========================================================================
// Fallback paths (R4 pk-f16 atomics; R2 f32 atomics)
// ===========================================================================
__global__ __launch_bounds__(256) void zero_ws_kernel(uint4* __restrict__ ws)
{
    const int total = ACC_WORDS / 4;
    int idx = blockIdx.x * 256 + threadIdx.x;
    if (idx < total) ws[idx] = make_uint4(0, 0, 0, 0);
}

__global__ __launch_bounds__(256) void conv_scatter_f16_kernel(
    const float* __restrict__ feat, const float* __restrict__ weight,
    const int* __restrict__ in_idx, const int* __restrict__ out_idx,
    __half2* __restrict__ acc)
{
    __shared__ float2 Wlds[NC * 16];
    const int k = blockIdx.y;
    const float2* wg = reinterpret_cast<const float2*>(weight + k * NC * NC);
    for (int t = threadIdx.x; t < NC * 16; t += 256)
        Wlds[t] = wg[t];
    __syncthreads();
    const int j = threadIdx.x & 15;
    const int g = threadIdx.x >> 4;
    float2 wcol[NC];
#pragma unroll
    for (int i = 0; i < NC; ++i) wcol[i] = Wlds[i * 16 + j];
    const int rbase = blockIdx.x * 64;
    for (int rr = g; rr < 64; rr += 16) {
        const int r = rbase + rr;
        const int irow = in_idx[(size_t)k * R_RULES + r];
        const int orow = out_idx[(size_t)k * R_RULES + r];
        const float4* fv = reinterpret_cast<const float4*>(feat + (size_t)irow * NC);
        float a0 = 0.0f, a1 = 0.0f;
#pragma unroll
        for (int i0 = 0; i0 < 8; ++i0) {
            const float4 f = fv[i0];
            a0 += f.x * wcol[i0*4+0].x;  a1 += f.x * wcol[i0*4+0].y;
            a0 += f.y * wcol[i0*4+1].x;  a1 += f.y * wcol[i0*4+1].y;
            a0 += f.z * wcol[i0*4+2].x;  a1 += f.z * wcol[i0*4+2].y;
            a0 += f.w * wcol[i0*4+3].x;  a1 += f.w * wcol[i0*4+3].y;
        }
        unsafeAtomicAdd(acc + (size_t)orow * 16 + j, __floats2half2_rn(a0, a1));
    }
}

__global__ __launch_bounds__(256) void unpack_kernel(
    const __half2* __restrict__ acc, const float* __restrict__ bias,
    float* __restrict__ out)
{
    int t = blockIdx.x * 256 + threadIdx.x;
    if (t >= ACC_WORDS) return;
    const int j = t & 15;
    const float2 v = __half22float2(acc[t]);
    const float2 b = reinterpret_cast<const float2*>(bias)[j];
    float2 o; o.x = v.x + b.x; o.y = v.y + b.y;
    reinterpret_cast<float2*>(out)[t] = o;
}

__global__ __launch_bounds__(256) void init_out_kernel(
    const float* __restrict__ bias, float* __restrict__ out)
{
    int idx = blockIdx.x * 256 + threadIdx.x;
    const int total4 = N_OUT_SZ * NC / 4;
    if (idx >= total4) return;
    int c0 = (idx * 4) & (NC - 1);
    float4 b;
    b.x = bias[c0+0]; b.y = bias[c0+1]; b.z = bias[c0+2]; b.w = bias[c0+3];
    reinterpret_cast<float4*>(out)[idx] = b;
}

__global__ __launch_bounds__(256) void conv_scatter_kernel(
    const float* __restrict__ feat, const float* __restrict__ weight,
    const int* __restrict__ in_idx, const int* __restrict__ out_idx,
    float* __restrict__ out)
{
    __shared__ float Wlds[NC * NC];
    const int k  = blockIdx.y;
    const int c  = threadIdx.x & (NC - 1);
    const int rg = threadIdx.x >> 5;
    for (int t = threadIdx.x; t < NC * NC; t += 256)
        Wlds[t] = weight[k * NC * NC + t];
    __syncthreads();
    float wcol[NC];
#pragma unroll
    for (int i = 0; i < NC; ++i) wcol[i] = Wlds[i * NC + c];
    const int rbase = blockIdx.x * 64;
    for (int rr = rg; rr < 64; rr += 8) {
        const int r = rbase + rr;
        const int irow = in_idx[(size_t)k * R_RULES + r];
        const int orow = out_idx[(size_t)k * R_RULES + r];
        const float4* fv = reinterpret_cast<const float4*>(feat + (size_t)irow * NC);
        float acc = 0.0f;
#pragma unroll
        for (int i0 = 0; i0 < 8; ++i0) {
            const float4 f = fv[i0];
            acc += f.x * wcol[i0*4+0];
            acc += f.y * wcol[i0*4+1];
            acc += f.z * wcol[i0*4+2];
            acc += f.w * wcol[i0*4+3];
        }
        atomicAdd(out + (size_t)orow * NC + c, acc);
    }
}

// ---------------------------------------------------------------------------
extern "C" void kernel_launch(void* const* d_in, const int* in_sizes, int n_in,
                              void* d_out, int out_size, void* d_ws, size_t ws_size,
                              hipStream_t stream)
{
    const float* feat    = (const float*)d_in[0];
    const float* weight  = (const float*)d_in[1];
    const float* bias    = (const float*)d_in[2];
    const int*   in_idx  = (const int*)d_in[3];
    const int*   out_idx = (const int*)d_in[4];
    float*       out     = (float*)d_out;

    if (ws_size >= WS_NEW_NEEDED) {
        char* ws = (char*)d_ws;
        u32* sorted = (u32*)(ws + SORT_OFF);
        u32* A      = (u32*)(ws + A_OFF);
        u32* bsum   = (u32*)(ws + BSUM_OFF);
        u32* boff   = (u32*)(ws + BOFF_OFF);

        zero_cnt_kernel<<<NSCANBLK, 256, 0, stream>>>((uint4*)A);
        {
            dim3 grid(HIST_BLK, K_OFF);
            hist_kernel<<<grid, 256, 0, stream>>>(out_idx, A);
        }
        blocksum_kernel<<<NSCANBLK, 256, 0, stream>>>((const uint4*)A, bsum);
        scanblk_kernel<<<1, 256, 0, stream>>>(bsum, boff);
        scanwrite_kernel<<<NSCANBLK, 256, 0, stream>>>((uint4*)A, boff);
        {
            dim3 grid(HIST_BLK, K_OFF);
            fill_kernel<<<grid, 256, 0, stream>>>(in_idx, out_idx, A, sorted);
        }
        gather_mfma_kernel<<<NCHUNK, 256, 0, stream>>>(feat, weight, sorted, A, bias, out);
    } else if (ws_size >= WS_F16_NEEDED) {
        __half2* acc = (__half2*)d_ws;
        zero_ws_kernel<<<(ACC_WORDS / 4 + 255) / 256, 256, 0, stream>>>((uint4*)d_ws);
        dim3 grid(R_RULES / 64, K_OFF);
        conv_scatter_f16_kernel<<<grid, 256, 0, stream>>>(feat, weight, in_idx, out_idx, acc);
        unpack_kernel<<<ACC_WORDS / 256, 256, 0, stream>>>(acc, bias, out);
    } else {
        int total4 = N_OUT_SZ * NC / 4;
        init_out_kernel<<<(total4 + 255) / 256, 256, 0, stream>>>(bias, out);
        dim3 grid(R_RULES / 64, K_OFF);
        conv_scatter_kernel<<<grid, 256, 0, stream>>>(feat, weight, in_idx, out_idx, out);
    }
}